// Round 6
// baseline (426.360 us; speedup 1.0000x reference)
//
#include <hip/hip_runtime.h>
#include <hip/hip_bf16.h>
#include <math.h>

#define NSTEPS 256
#define GRIDN  160
#define NVOX   (160 * 160 * 160)
#define NBINS  512   // 8x8x8 bins of 40mm over [-160,160]^3

// ---------- image -> bf16 copy (halves gather footprint) ----------
__global__ __launch_bounds__(256) void convert_kernel(
    const float4* __restrict__ image, ushort4* __restrict__ imgb, int n4)
{
    const int i = blockIdx.x * blockDim.x + threadIdx.x;
    if (i >= n4) return;
    const float4 x = image[i];
    __hip_bfloat16 a = __float2bfloat16(x.x);
    __hip_bfloat16 b = __float2bfloat16(x.y);
    __hip_bfloat16 c = __float2bfloat16(x.z);
    __hip_bfloat16 d = __float2bfloat16(x.w);
    ushort4 o;
    o.x = *reinterpret_cast<unsigned short*>(&a);
    o.y = *reinterpret_cast<unsigned short*>(&b);
    o.z = *reinterpret_cast<unsigned short*>(&c);
    o.w = *reinterpret_cast<unsigned short*>(&d);
    imgb[i] = o;
}

// ---------- bin by TOF-window center ----------
__global__ __launch_bounds__(256) void count_kernel(
    const float* __restrict__ lors, int* __restrict__ hist,
    int* __restrict__ binidx, int n)
{
    const int i = blockIdx.x * blockDim.x + threadIdx.x;
    if (i >= n) return;
    const float* l = lors + (size_t)i * 7;
    const float p0x = l[0], p0y = l[1], p0z = l[2];
    const float dx = l[3] - p0x, dy = l[4] - p0y, dz = l[5] - p0z;
    const float L = sqrtf(dx * dx + dy * dy + dz * dz);
    float tc = 0.5f + (l[6] * 0.15f) / L;
    if (!(tc >= 0.0f)) tc = 0.0f;   // NaN-safe
    if (tc > 1.0f)     tc = 1.0f;
    const float cx = p0x + tc * dx;
    const float cy = p0y + tc * dy;
    const float cz = p0z + tc * dz;
    int bx = (int)floorf((cx + 160.0f) * 0.025f); bx = min(max(bx, 0), 7);
    int by = (int)floorf((cy + 160.0f) * 0.025f); by = min(max(by, 0), 7);
    int bz = (int)floorf((cz + 160.0f) * 0.025f); bz = min(max(bz, 0), 7);
    const int b = (bx << 6) | (by << 3) | bz;
    binidx[i] = b;
    atomicAdd(&hist[b], 1);
}

// ---------- exclusive scan over 512 bins (one block) ----------
__global__ __launch_bounds__(512) void scan_kernel(
    const int* __restrict__ hist, int* __restrict__ cursor)
{
    __shared__ int tmp[NBINS];
    const int t = threadIdx.x;
    tmp[t] = hist[t];
    __syncthreads();
    for (int off = 1; off < NBINS; off <<= 1) {
        int v = 0;
        if (t >= off) v = tmp[t - off];
        __syncthreads();
        tmp[t] += v;
        __syncthreads();
    }
    cursor[t] = tmp[t] - hist[t];   // exclusive = inclusive - own
}

// ---------- scatter LORs into bin-sorted order (precompute d, L) ----------
__global__ __launch_bounds__(256) void reorder_kernel(
    const float* __restrict__ lors, const int* __restrict__ binidx,
    int* __restrict__ cursor, float4* __restrict__ sorted, int n)
{
    const int i = blockIdx.x * blockDim.x + threadIdx.x;
    if (i >= n) return;
    const int slot = atomicAdd(&cursor[binidx[i]], 1);
    const float* l = lors + (size_t)i * 7;
    const float p0x = l[0], p0y = l[1], p0z = l[2];
    const float dx = l[3] - p0x, dy = l[4] - p0y, dz = l[5] - p0z;
    const float L = sqrtf(dx * dx + dy * dy + dz * dz);
    sorted[(size_t)slot * 2]     = make_float4(p0x, p0y, p0z, l[6]);
    sorted[(size_t)slot * 2 + 1] = make_float4(dx, dy, dz, L);
}

// ---------- main trace: one wave per sorted LOR, XCD-chunked ----------
__global__ __launch_bounds__(256) void trace_sorted_kernel(
    const __hip_bfloat16* __restrict__ imgb,
    const float4* __restrict__ sorted,
    float* __restrict__ bp,
    int n, int chunk)
{
#pragma clang fp contract(off)
    const int v    = threadIdx.x >> 6;
    const int lane = threadIdx.x & 63;
    const int xcd  = blockIdx.x & 7;          // round-robin XCD heuristic
    const int ci   = ((int)(blockIdx.x >> 3)) * 4 + v;
    if (ci >= chunk) return;
    const int i = xcd * chunk + ci;
    if (i >= n) return;

    const float4 A = sorted[(size_t)i * 2];
    const float4 B = sorted[(size_t)i * 2 + 1];
    const float p0x = A.x, p0y = A.y, p0z = A.z, tof = A.w;
    const float dx = B.x, dy = B.y, dz = B.z, L = B.w;

    const float dl = L * (1.0f / NSTEPS);
    const float s_tof = tof * 0.15f;                 // C_HALF
    const float SIGMA = (float)(45.0 / 2.355);       // f32(TIME_RES*C_HALF/2.355)

    // analytic window: Gaussian support e<10 (|u|<4.472) ∩ box, ±2-step margin
    const float CUTS = 4.4721360f * SIGMA;
    float t0, t1;
    {
        const float invL = 1.0f / L;
        t0 = 0.5f + (s_tof - CUTS) * invL;
        t1 = 0.5f + (s_tof + CUTS) * invL;
        if (t0 > t1) { const float tmp = t0; t0 = t1; t1 = tmp; }
        const float pc[3] = {p0x, p0y, p0z};
        const float dc[3] = {dx, dy, dz};
        #pragma unroll
        for (int a = 0; a < 3; ++a) {
            if (dc[a] != 0.0f) {
                const float inv = 1.0f / dc[a];
                const float ta = (-160.0f - pc[a]) * inv;
                const float tb = ( 160.0f - pc[a]) * inv;
                t0 = fmaxf(t0, fminf(ta, tb));
                t1 = fminf(t1, fmaxf(ta, tb));
            } else if (pc[a] < -160.0f || pc[a] >= 160.0f) {
                t1 = -1.0f;
            }
        }
        t0 = fmaxf(t0, 0.0f);
        t1 = fminf(t1, 1.0f);
    }
    int j0 = (int)floorf(t0 * 256.0f - 0.5f) - 2;
    int j1 = (int)ceilf (t1 * 256.0f - 0.5f) + 2;
    if (!(t0 <= t1)) { j0 = 0; j1 = -1; }
    j0 = max(j0, 0);
    j1 = min(j1, NSTEPS - 1);
    const int nk = (j1 - j0 + 64) >> 6;
    if (nk <= 0) return;                             // wave-uniform

    int   flat[4];
    float w[4];
    float psum = 0.0f;

    for (int k = 0; k < nk; ++k) {
        const int j = j0 + lane + (k << 6);
        const float t = (j + 0.5f) * (1.0f / NSTEPS);
        // exact f32 geometry (no fma): must match numpy f32 floor decisions
        const float px = p0x + t * dx;
        const float py = p0y + t * dy;
        const float pz = p0z + t * dz;
        const float fx = floorf((px + 160.0f) * 0.5f);
        const float fy = floorf((py + 160.0f) * 0.5f);
        const float fz = floorf((pz + 160.0f) * 0.5f);
        const bool inb = (j <= j1) &
                         (fx >= 0.0f) & (fx < 160.0f) &
                         (fy >= 0.0f) & (fy < 160.0f) &
                         (fz >= 0.0f) & (fz < 160.0f);
        const float s = (t - 0.5f) * L;
        const float u = (s - s_tof) / SIGMA;
        const float e = 0.5f * (u * u);

        float wk = 0.0f;
        int   fl = 0;
        if (inb && e < 10.0f) {
            wk = expf(-e) * dl;
            fl = (int)fx * (GRIDN * GRIDN) + (int)fy * GRIDN + (int)fz;
            psum += __bfloat162float(imgb[fl]) * wk;
        }
        flat[k] = fl;
        w[k]    = wk;
    }

    #pragma unroll
    for (int off = 32; off >= 1; off >>= 1)
        psum += __shfl_xor(psum, off, 64);

    for (int k = 0; k < nk; ++k) {
        if (w[k] > 0.0f)
            atomicAdd(&bp[flat[k]], psum * w[k]);
    }
}

// ---------- fallback (R5): direct trace, fp32 image ----------
__global__ __launch_bounds__(256) void trace_direct_kernel(
    const float* __restrict__ image,
    const float* __restrict__ lors,
    float* __restrict__ bp,
    int n_lors)
{
#pragma clang fp contract(off)
    const int wave = (int)((blockIdx.x * blockDim.x + threadIdx.x) >> 6);
    const int lane = threadIdx.x & 63;
    if (wave >= n_lors) return;
    const float* l = lors + (size_t)wave * 7;
    const float p0x = l[0], p0y = l[1], p0z = l[2];
    const float dx = l[3] - p0x, dy = l[4] - p0y, dz = l[5] - p0z;
    const float tof = l[6];
    const float L  = sqrtf(dx * dx + dy * dy + dz * dz);
    const float dl = L * (1.0f / NSTEPS);
    const float s_tof = tof * 0.15f;
    const float SIGMA = (float)(45.0 / 2.355);
    const float CUTS = 4.4721360f * SIGMA;
    float t0, t1;
    {
        const float invL = 1.0f / L;
        t0 = 0.5f + (s_tof - CUTS) * invL;
        t1 = 0.5f + (s_tof + CUTS) * invL;
        if (t0 > t1) { const float tmp = t0; t0 = t1; t1 = tmp; }
        const float pc[3] = {p0x, p0y, p0z};
        const float dc[3] = {dx, dy, dz};
        #pragma unroll
        for (int a = 0; a < 3; ++a) {
            if (dc[a] != 0.0f) {
                const float inv = 1.0f / dc[a];
                const float ta = (-160.0f - pc[a]) * inv;
                const float tb = ( 160.0f - pc[a]) * inv;
                t0 = fmaxf(t0, fminf(ta, tb));
                t1 = fminf(t1, fmaxf(ta, tb));
            } else if (pc[a] < -160.0f || pc[a] >= 160.0f) t1 = -1.0f;
        }
        t0 = fmaxf(t0, 0.0f);
        t1 = fminf(t1, 1.0f);
    }
    int j0 = (int)floorf(t0 * 256.0f - 0.5f) - 2;
    int j1 = (int)ceilf (t1 * 256.0f - 0.5f) + 2;
    if (!(t0 <= t1)) { j0 = 0; j1 = -1; }
    j0 = max(j0, 0); j1 = min(j1, NSTEPS - 1);
    const int nk = (j1 - j0 + 64) >> 6;
    if (nk <= 0) return;
    int flat[4]; float w[4]; float psum = 0.0f;
    for (int k = 0; k < nk; ++k) {
        const int j = j0 + lane + (k << 6);
        const float t = (j + 0.5f) * (1.0f / NSTEPS);
        const float px = p0x + t * dx, py = p0y + t * dy, pz = p0z + t * dz;
        const float fx = floorf((px + 160.0f) * 0.5f);
        const float fy = floorf((py + 160.0f) * 0.5f);
        const float fz = floorf((pz + 160.0f) * 0.5f);
        const bool inb = (j <= j1) & (fx >= 0.0f) & (fx < 160.0f) &
                         (fy >= 0.0f) & (fy < 160.0f) & (fz >= 0.0f) & (fz < 160.0f);
        const float s = (t - 0.5f) * L;
        const float u = (s - s_tof) / SIGMA;
        const float e = 0.5f * (u * u);
        float wk = 0.0f; int fl = 0;
        if (inb && e < 10.0f) {
            wk = expf(-e) * dl;
            fl = (int)fx * (GRIDN * GRIDN) + (int)fy * GRIDN + (int)fz;
            psum += image[fl] * wk;
        }
        flat[k] = fl; w[k] = wk;
    }
    #pragma unroll
    for (int off = 32; off >= 1; off >>= 1) psum += __shfl_xor(psum, off, 64);
    for (int k = 0; k < nk; ++k)
        if (w[k] > 0.0f) atomicAdd(&bp[flat[k]], psum * w[k]);
}

// ---------- out = image / (effmap + eps) * bp ----------
__global__ __launch_bounds__(256) void finalize_kernel(
    const float4* __restrict__ image,
    const float4* __restrict__ effmap,
    float4* __restrict__ out,
    int n4)
{
    const int i = blockIdx.x * blockDim.x + threadIdx.x;
    if (i >= n4) return;
    const float4 im = image[i];
    const float4 ef = effmap[i];
    float4 b = out[i];
    b.x = im.x / (ef.x + 1e-8f) * b.x;
    b.y = im.y / (ef.y + 1e-8f) * b.y;
    b.z = im.z / (ef.z + 1e-8f) * b.z;
    b.w = im.w / (ef.w + 1e-8f) * b.w;
    out[i] = b;
}

extern "C" void kernel_launch(void* const* d_in, const int* in_sizes, int n_in,
                              void* d_out, int out_size, void* d_ws, size_t ws_size,
                              hipStream_t stream) {
    const float* image  = (const float*)d_in[0];
    const float* effmap = (const float*)d_in[1];
    const float* lors   = (const float*)d_in[2];
    float* out = (float*)d_out;
    const int n = in_sizes[2] / 7;

    char* ws = (char*)d_ws;
    const size_t bin_off    = 4096;
    const size_t sorted_off = bin_off + (((size_t)n * 4 + 255) & ~(size_t)255);
    const size_t imgb_off   = sorted_off + (size_t)n * 32;
    const size_t total      = imgb_off + (size_t)NVOX * 2;

    // bp accumulator lives in d_out; zero it (harness poisons with 0xAA)
    hipMemsetAsync(out, 0, (size_t)NVOX * sizeof(float), stream);

    if (ws_size >= total) {
        int*    hist   = (int*)ws;
        int*    cursor = (int*)(ws + 2048);
        int*    binidx = (int*)(ws + bin_off);
        float4* sorted = (float4*)(ws + sorted_off);
        __hip_bfloat16* imgb = (__hip_bfloat16*)(ws + imgb_off);

        hipMemsetAsync(hist, 0, NBINS * sizeof(int), stream);
        convert_kernel<<<(NVOX / 4 + 255) / 256, 256, 0, stream>>>(
            (const float4*)image, (ushort4*)imgb, NVOX / 4);
        count_kernel<<<(n + 255) / 256, 256, 0, stream>>>(lors, hist, binidx, n);
        scan_kernel<<<1, 512, 0, stream>>>(hist, cursor);
        reorder_kernel<<<(n + 255) / 256, 256, 0, stream>>>(lors, binidx, cursor, sorted, n);

        const int chunk = (n + 7) / 8;
        const int Bc = (chunk + 3) / 4;       // 4 waves per block
        trace_sorted_kernel<<<8 * Bc, 256, 0, stream>>>(imgb, sorted, out, n, chunk);
    } else {
        const int blocks = (n + 3) / 4;       // 4 waves per block
        trace_direct_kernel<<<blocks, 256, 0, stream>>>(image, lors, out, n);
    }

    const int n4 = NVOX / 4;
    finalize_kernel<<<(n4 + 255) / 256, 256, 0, stream>>>(
        (const float4*)image, (const float4*)effmap, (float4*)out, n4);
}

// Round 7
// 297.270 us; speedup vs baseline: 1.4343x; 1.4343x over previous
//
#include <hip/hip_runtime.h>
#include <math.h>

#define NSTEPS 256
#define GRIDN  160
#define NVOX   (160 * 160 * 160)
#define NTPA   20                  // tiles per axis (8^3-voxel tiles)
#define NTILES (NTPA * NTPA * NTPA)
#define ITEM_CAP (4 * 1024 * 1024)

struct LorT { float4 a; float4 b; };   // a: p0.xyz, tof ; b: d.xyz, L

// ---- shared exact math (contract OFF: must bit-match f32 numpy floor path) ----
__device__ __forceinline__ void lor_window(
    float p0x, float p0y, float p0z, float dx, float dy, float dz,
    float L, float s_tof, int& j0, int& j1)
{
#pragma clang fp contract(off)
    const float SIGMA = (float)(45.0 / 2.355);
    const float CUTS  = 4.4721360f * SIGMA;      // e<10 support
    const float invL = 1.0f / L;
    float t0 = 0.5f + (s_tof - CUTS) * invL;
    float t1 = 0.5f + (s_tof + CUTS) * invL;
    if (t0 > t1) { const float tmp = t0; t0 = t1; t1 = tmp; }
    const float pc[3] = {p0x, p0y, p0z};
    const float dc[3] = {dx, dy, dz};
    #pragma unroll
    for (int a = 0; a < 3; ++a) {
        if (dc[a] != 0.0f) {
            const float inv = 1.0f / dc[a];
            const float ta = (-160.0f - pc[a]) * inv;
            const float tb = ( 160.0f - pc[a]) * inv;
            t0 = fmaxf(t0, fminf(ta, tb));
            t1 = fminf(t1, fmaxf(ta, tb));
        } else if (pc[a] < -160.0f || pc[a] >= 160.0f) t1 = -1.0f;
    }
    t0 = fmaxf(t0, 0.0f);
    t1 = fminf(t1, 1.0f);
    j0 = (int)floorf(t0 * 256.0f - 0.5f) - 2;
    j1 = (int)ceilf (t1 * 256.0f - 0.5f) + 2;
    if (!(t0 <= t1)) { j0 = 0; j1 = -1; }
    j0 = max(j0, 0);
    j1 = min(j1, NSTEPS - 1);
}

__device__ __forceinline__ bool eval_sample(
    int j, int j1, float p0x, float p0y, float p0z,
    float dx, float dy, float dz, float L, float dl, float s_tof,
    int& ix, int& iy, int& iz, float& wk)
{
#pragma clang fp contract(off)
    const float SIGMA = (float)(45.0 / 2.355);
    const float t = (j + 0.5f) * (1.0f / 256.0f);
    const float px = p0x + t * dx;
    const float py = p0y + t * dy;
    const float pz = p0z + t * dz;
    const float fx = floorf((px + 160.0f) * 0.5f);
    const float fy = floorf((py + 160.0f) * 0.5f);
    const float fz = floorf((pz + 160.0f) * 0.5f);
    const bool inb = (j <= j1) &
                     (fx >= 0.0f) & (fx < 160.0f) &
                     (fy >= 0.0f) & (fy < 160.0f) &
                     (fz >= 0.0f) & (fz < 160.0f);
    const float s = (t - 0.5f) * L;
    const float u = (s - s_tof) / SIGMA;
    const float e = 0.5f * (u * u);
    wk = 0.0f;
    if (inb && e < 10.0f) {
        wk = expf(-e) * dl;
        ix = (int)fx; iy = (int)fy; iz = (int)fz;
        return true;
    }
    return false;
}

// ---- emission: one wave per LOR; run-length compaction of per-sample tiles ----
// phase 0: count runs per tile (+build lortab); phase 1: fill grouped item array
__global__ __launch_bounds__(256) void emit_kernel(
    const float* __restrict__ lors, LorT* __restrict__ lortab,
    int* __restrict__ histcur, unsigned* __restrict__ items,
    int n, int phase)
{
#pragma clang fp contract(off)
    const int wave = (int)((blockIdx.x * blockDim.x + threadIdx.x) >> 6);
    const int lane = threadIdx.x & 63;
    if (wave >= n) return;

    float p0x, p0y, p0z, tof, dx, dy, dz, L;
    if (phase == 0) {
        const float* l = lors + (size_t)wave * 7;
        p0x = l[0]; p0y = l[1]; p0z = l[2];
        dx = l[3] - p0x; dy = l[4] - p0y; dz = l[5] - p0z; tof = l[6];
        L = sqrtf(dx * dx + dy * dy + dz * dz);
        if (lane == 0) {
            lortab[wave].a = make_float4(p0x, p0y, p0z, tof);
            lortab[wave].b = make_float4(dx, dy, dz, L);
        }
    } else {
        const float4 A = lortab[wave].a, B = lortab[wave].b;
        p0x = A.x; p0y = A.y; p0z = A.z; tof = A.w;
        dx  = B.x; dy  = B.y; dz  = B.z; L   = B.w;
    }
    const float dl = L * (1.0f / 256.0f);
    const float s_tof = tof * 0.15f;
    int j0, j1;
    lor_window(p0x, p0y, p0z, dx, dy, dz, L, s_tof, j0, j1);
    const int nk = (j1 - j0 + 64) >> 6;

    for (int k = 0; k < nk; ++k) {
        const int j = j0 + lane + (k << 6);
        int ix, iy, iz; float wk;
        const bool valid = eval_sample(j, j1, p0x, p0y, p0z, dx, dy, dz, L, dl, s_tof,
                                       ix, iy, iz, wk);
        const unsigned key = valid
            ? (unsigned)((ix >> 3) * 400 + (iy >> 3) * 20 + (iz >> 3))
            : 0xFFFFFFFFu;
        const unsigned prev = __shfl_up(key, 1, 64);
        const bool chg = (lane == 0) || (prev != key);
        const unsigned long long cm = __ballot(chg);
        if (chg && valid) {
            const unsigned long long above = cm & ~((2ULL << lane) - 1ULL);
            const int nxt = above ? (__ffsll((unsigned long long)above) - 1) : 64;
            const int len = nxt - lane;                 // 1..64 (really <=~12)
            if (phase == 0) {
                atomicAdd(&histcur[key], 1);
            } else {
                const int slot = atomicAdd(&histcur[key], 1);
                if (slot < ITEM_CAP)
                    items[slot] = ((unsigned)wave << 14) | ((unsigned)j << 6)
                                | (unsigned)(len - 1);
            }
        }
    }
}

// ---- exclusive scan over NTILES bins (single 1024-thread block, 8 bins/thread) ----
__global__ __launch_bounds__(1024) void scan_kernel(
    const int* __restrict__ hist, int* __restrict__ offs, int* __restrict__ cursor)
{
    __shared__ int part[1024];
    const int t = threadIdx.x;
    const int base = t * 8;
    int loc[8]; int s = 0;
    #pragma unroll
    for (int i = 0; i < 8; ++i) {
        const int h = (base + i < NTILES) ? hist[base + i] : 0;
        loc[i] = s; s += h;
    }
    part[t] = s;
    __syncthreads();
    for (int off = 1; off < 1024; off <<= 1) {
        int v = 0;
        if (t >= off) v = part[t - off];
        __syncthreads();
        part[t] += v;
        __syncthreads();
    }
    const int excl = (t > 0) ? part[t - 1] : 0;
    #pragma unroll
    for (int i = 0; i < 8; ++i) {
        if (base + i < NTILES) {
            offs[base + i]   = excl + loc[i];
            cursor[base + i] = excl + loc[i];
        }
    }
    if (t == 1023) offs[NTILES] = part[1023];
}

// ---- pass A: per-tile forward; image tile in LDS, partial p via small atomics ----
__global__ __launch_bounds__(256) void tileA_kernel(
    const float* __restrict__ image, const LorT* __restrict__ lortab,
    const int* __restrict__ offs, const unsigned* __restrict__ items,
    float* __restrict__ p)
{
    const int b = blockIdx.x;
    const int i0 = offs[b], i1 = min(offs[b + 1], ITEM_CAP);
    if (i0 >= i1) return;
    const int tx0 = (b / 400) << 3, ty0 = ((b / 20) % 20) << 3, tz0 = (b % 20) << 3;
    __shared__ float img[512];
    const int t = threadIdx.x;
    for (int v = t; v < 512; v += 256) {
        const int lx = v >> 6, ly = (v >> 3) & 7, lz = v & 7;
        img[v] = image[(size_t)(tx0 + lx) * 25600 + (ty0 + ly) * 160 + (tz0 + lz)];
    }
    __syncthreads();
    for (int idx = i0 + t; idx < i1; idx += 256) {
        const unsigned it = items[idx];
        const int lor = (int)(it >> 14);
        const int js  = (int)((it >> 6) & 255);
        const int len = (int)(it & 63) + 1;
        const float4 A = lortab[lor].a, B = lortab[lor].b;
        const float dl = B.w * (1.0f / 256.0f);
        const float s_tof = A.w * 0.15f;
        float pp = 0.0f;
        for (int m = 0; m < len; ++m) {
            int ix, iy, iz; float wk;
            if (eval_sample(js + m, 255, A.x, A.y, A.z, B.x, B.y, B.z, B.w, dl, s_tof,
                            ix, iy, iz, wk)) {
                const int lx = ix - tx0, ly = iy - ty0, lz = iz - tz0;
                if ((unsigned)lx < 8u && (unsigned)ly < 8u && (unsigned)lz < 8u)
                    pp += img[(lx << 6) | (ly << 3) | lz] * wk;
            }
        }
        atomicAdd(&p[lor], pp);
    }
}

// ---- pass B: per-tile backprojection; LDS accumulate, ONE coalesced store ----
__global__ __launch_bounds__(256) void tileB_kernel(
    const LorT* __restrict__ lortab, const int* __restrict__ offs,
    const unsigned* __restrict__ items, const float* __restrict__ p,
    float* __restrict__ bp)
{
    const int b = blockIdx.x;
    const int i0 = offs[b], i1 = min(offs[b + 1], ITEM_CAP);
    if (i0 >= i1) return;
    const int tx0 = (b / 400) << 3, ty0 = ((b / 20) % 20) << 3, tz0 = (b % 20) << 3;
    __shared__ float acc[512];
    const int t = threadIdx.x;
    for (int v = t; v < 512; v += 256) acc[v] = 0.0f;
    __syncthreads();
    for (int idx = i0 + t; idx < i1; idx += 256) {
        const unsigned it = items[idx];
        const int lor = (int)(it >> 14);
        const int js  = (int)((it >> 6) & 255);
        const int len = (int)(it & 63) + 1;
        const float4 A = lortab[lor].a, B = lortab[lor].b;
        const float dl = B.w * (1.0f / 256.0f);
        const float s_tof = A.w * 0.15f;
        const float pv = p[lor];
        for (int m = 0; m < len; ++m) {
            int ix, iy, iz; float wk;
            if (eval_sample(js + m, 255, A.x, A.y, A.z, B.x, B.y, B.z, B.w, dl, s_tof,
                            ix, iy, iz, wk)) {
                const int lx = ix - tx0, ly = iy - ty0, lz = iz - tz0;
                if ((unsigned)lx < 8u && (unsigned)ly < 8u && (unsigned)lz < 8u)
                    atomicAdd(&acc[(lx << 6) | (ly << 3) | lz], pv * wk);
            }
        }
    }
    __syncthreads();
    for (int v = t; v < 512; v += 256) {
        const int lx = v >> 6, ly = (v >> 3) & 7, lz = v & 7;
        bp[(size_t)(tx0 + lx) * 25600 + (ty0 + ly) * 160 + (tz0 + lz)] = acc[v];
    }
}

// ---- fallback (R5): direct trace with global atomics ----
__global__ __launch_bounds__(256) void trace_direct_kernel(
    const float* __restrict__ image, const float* __restrict__ lors,
    float* __restrict__ bp, int n_lors)
{
#pragma clang fp contract(off)
    const int wave = (int)((blockIdx.x * blockDim.x + threadIdx.x) >> 6);
    const int lane = threadIdx.x & 63;
    if (wave >= n_lors) return;
    const float* l = lors + (size_t)wave * 7;
    const float p0x = l[0], p0y = l[1], p0z = l[2];
    const float dx = l[3] - p0x, dy = l[4] - p0y, dz = l[5] - p0z;
    const float tof = l[6];
    const float L  = sqrtf(dx * dx + dy * dy + dz * dz);
    const float dl = L * (1.0f / 256.0f);
    const float s_tof = tof * 0.15f;
    int j0, j1;
    lor_window(p0x, p0y, p0z, dx, dy, dz, L, s_tof, j0, j1);
    const int nk = (j1 - j0 + 64) >> 6;
    if (nk <= 0) return;
    int flat[4]; float w[4]; float psum = 0.0f;
    for (int k = 0; k < nk; ++k) {
        const int j = j0 + lane + (k << 6);
        int ix, iy, iz; float wk = 0.0f; int fl = 0;
        if (eval_sample(j, j1, p0x, p0y, p0z, dx, dy, dz, L, dl, s_tof, ix, iy, iz, wk)) {
            fl = ix * 25600 + iy * 160 + iz;
            psum += image[fl] * wk;
        }
        flat[k] = fl; w[k] = wk;
    }
    #pragma unroll
    for (int off = 32; off >= 1; off >>= 1) psum += __shfl_xor(psum, off, 64);
    for (int k = 0; k < nk; ++k)
        if (w[k] > 0.0f) atomicAdd(&bp[flat[k]], psum * w[k]);
}

// ---- out = image / (effmap + eps) * bp ----
__global__ __launch_bounds__(256) void finalize_kernel(
    const float4* __restrict__ image, const float4* __restrict__ effmap,
    float4* __restrict__ out, int n4)
{
    const int i = blockIdx.x * blockDim.x + threadIdx.x;
    if (i >= n4) return;
    const float4 im = image[i];
    const float4 ef = effmap[i];
    float4 b = out[i];
    b.x = im.x / (ef.x + 1e-8f) * b.x;
    b.y = im.y / (ef.y + 1e-8f) * b.y;
    b.z = im.z / (ef.z + 1e-8f) * b.z;
    b.w = im.w / (ef.w + 1e-8f) * b.w;
    out[i] = b;
}

extern "C" void kernel_launch(void* const* d_in, const int* in_sizes, int n_in,
                              void* d_out, int out_size, void* d_ws, size_t ws_size,
                              hipStream_t stream) {
    const float* image  = (const float*)d_in[0];
    const float* effmap = (const float*)d_in[1];
    const float* lors   = (const float*)d_in[2];
    float* out = (float*)d_out;
    const int n = in_sizes[2] / 7;

    // ws layout
    char* ws = (char*)d_ws;
    const size_t hist_off   = 0;
    const size_t offs_off   = hist_off + 32768;                    // NTILES*4 = 32000
    const size_t cursor_off = offs_off + 32768;                    // (NTILES+1)*4
    const size_t p_off      = cursor_off + 32768;
    const size_t lortab_off = p_off + (((size_t)n * 4 + 255) & ~(size_t)255);
    const size_t items_off  = lortab_off + (size_t)n * sizeof(LorT);
    const size_t total      = items_off + (size_t)ITEM_CAP * 4;

    hipMemsetAsync(out, 0, (size_t)NVOX * sizeof(float), stream);

    if (ws_size >= total && n < (1 << 18)) {
        int*      hist   = (int*)(ws + hist_off);
        int*      offs   = (int*)(ws + offs_off);
        int*      cursor = (int*)(ws + cursor_off);
        float*    p      = (float*)(ws + p_off);
        LorT*     lortab = (LorT*)(ws + lortab_off);
        unsigned* items  = (unsigned*)(ws + items_off);

        hipMemsetAsync(hist, 0, NTILES * sizeof(int), stream);
        hipMemsetAsync(p, 0, (size_t)n * sizeof(float), stream);

        const int blocksE = (n + 3) / 4;   // 4 waves/block, wave per LOR
        emit_kernel<<<blocksE, 256, 0, stream>>>(lors, lortab, hist, items, n, 0);
        scan_kernel<<<1, 1024, 0, stream>>>(hist, offs, cursor);
        emit_kernel<<<blocksE, 256, 0, stream>>>(lors, lortab, cursor, items, n, 1);
        tileA_kernel<<<NTILES, 256, 0, stream>>>(image, lortab, offs, items, p);
        tileB_kernel<<<NTILES, 256, 0, stream>>>(lortab, offs, items, p, out);
    } else {
        trace_direct_kernel<<<(n + 3) / 4, 256, 0, stream>>>(image, lors, out, n);
    }

    const int n4 = NVOX / 4;
    finalize_kernel<<<(n4 + 255) / 256, 256, 0, stream>>>(
        (const float4*)image, (const float4*)effmap, (float4*)out, n4);
}

// Round 8
// 282.398 us; speedup vs baseline: 1.5098x; 1.0527x over previous
//
#include <hip/hip_runtime.h>
#include <math.h>

#define NSTEPS 256
#define GRIDN  160
#define NVOX   (160 * 160 * 160)
#define NTPA   20                  // tiles per axis (8^3-voxel tiles)
#define NTILES (NTPA * NTPA * NTPA)
#define ITEM_CAP (4 * 1024 * 1024)

#define INV_SIGMA 0.05233333f      // 2.355/45, fast path (weight only)

struct LorT { float4 a; float4 b; };   // a: p0.xyz, tof ; b: d.xyz, L

// ---- strict voxel path (contract OFF: bit-match f32 numpy floor decisions)
//      + fast validity e (weight tolerance is huge; predicate shared by all users)
__device__ __forceinline__ bool sample_vox(
    int j, float p0x, float p0y, float p0z,
    float dx, float dy, float dz, float L, float s_tof,
    int& ix, int& iy, int& iz, float& e)
{
#pragma clang fp contract(off)
    const float t = (j + 0.5f) * (1.0f / 256.0f);
    const float px = p0x + t * dx;
    const float py = p0y + t * dy;
    const float pz = p0z + t * dz;
    const float fx = floorf((px + 160.0f) * 0.5f);
    const float fy = floorf((py + 160.0f) * 0.5f);
    const float fz = floorf((pz + 160.0f) * 0.5f);
    const bool inb = (fx >= 0.0f) & (fx < 160.0f) &
                     (fy >= 0.0f) & (fy < 160.0f) &
                     (fz >= 0.0f) & (fz < 160.0f);
    const float s = (t - 0.5f) * L;
    const float u = (s - s_tof) * INV_SIGMA;   // fast: mul, not strict div
    e = 0.5f * (u * u);
    if (inb & (e < 10.0f)) {
        ix = (int)fx; iy = (int)fy; iz = (int)fz;
        return true;
    }
    return false;
}

__device__ __forceinline__ void lor_window(
    float p0x, float p0y, float p0z, float dx, float dy, float dz,
    float L, float s_tof, int& j0, int& j1)
{
#pragma clang fp contract(off)
    const float SIGMA = (float)(45.0 / 2.355);
    const float CUTS  = 4.4721360f * SIGMA;      // e<10 support
    const float invL = 1.0f / L;
    float t0 = 0.5f + (s_tof - CUTS) * invL;
    float t1 = 0.5f + (s_tof + CUTS) * invL;
    if (t0 > t1) { const float tmp = t0; t0 = t1; t1 = tmp; }
    const float pc[3] = {p0x, p0y, p0z};
    const float dc[3] = {dx, dy, dz};
    #pragma unroll
    for (int a = 0; a < 3; ++a) {
        if (dc[a] != 0.0f) {
            const float inv = 1.0f / dc[a];
            const float ta = (-160.0f - pc[a]) * inv;
            const float tb = ( 160.0f - pc[a]) * inv;
            t0 = fmaxf(t0, fminf(ta, tb));
            t1 = fminf(t1, fmaxf(ta, tb));
        } else if (pc[a] < -160.0f || pc[a] >= 160.0f) t1 = -1.0f;
    }
    t0 = fmaxf(t0, 0.0f);
    t1 = fminf(t1, 1.0f);
    j0 = (int)floorf(t0 * 256.0f - 0.5f) - 2;
    j1 = (int)ceilf (t1 * 256.0f - 0.5f) + 2;
    if (!(t0 <= t1)) { j0 = 0; j1 = -1; }
    j0 = max(j0, 0);
    j1 = min(j1, NSTEPS - 1);
}

// ---- emission: one wave per LOR; run-length compaction; NO weight math ----
__global__ __launch_bounds__(256) void emit_kernel(
    const float* __restrict__ lors, LorT* __restrict__ lortab,
    int* __restrict__ histcur, unsigned* __restrict__ items,
    int n, int phase)
{
#pragma clang fp contract(off)
    const int wave = (int)((blockIdx.x * blockDim.x + threadIdx.x) >> 6);
    const int lane = threadIdx.x & 63;
    if (wave >= n) return;

    float p0x, p0y, p0z, tof, dx, dy, dz, L;
    if (phase == 0) {
        const float* l = lors + (size_t)wave * 7;
        p0x = l[0]; p0y = l[1]; p0z = l[2];
        dx = l[3] - p0x; dy = l[4] - p0y; dz = l[5] - p0z; tof = l[6];
        L = sqrtf(dx * dx + dy * dy + dz * dz);
        if (lane == 0) {
            lortab[wave].a = make_float4(p0x, p0y, p0z, tof);
            lortab[wave].b = make_float4(dx, dy, dz, L);
        }
    } else {
        const float4 A = lortab[wave].a, B = lortab[wave].b;
        p0x = A.x; p0y = A.y; p0z = A.z; tof = A.w;
        dx  = B.x; dy  = B.y; dz  = B.z; L   = B.w;
    }
    const float s_tof = tof * 0.15f;
    int j0, j1;
    lor_window(p0x, p0y, p0z, dx, dy, dz, L, s_tof, j0, j1);
    const int nk = (j1 - j0 + 64) >> 6;

    for (int k = 0; k < nk; ++k) {
        const int j = j0 + lane + (k << 6);
        int ix, iy, iz; float e;
        const bool valid = (j <= j1) &&
            sample_vox(j, p0x, p0y, p0z, dx, dy, dz, L, s_tof, ix, iy, iz, e);
        const unsigned key = valid
            ? (unsigned)((ix >> 3) * 400 + (iy >> 3) * 20 + (iz >> 3))
            : 0xFFFFFFFFu;
        const unsigned prev = __shfl_up(key, 1, 64);
        const bool chg = (lane == 0) || (prev != key);
        const unsigned long long cm = __ballot(chg);
        if (chg && valid) {
            const unsigned long long above = cm & ~((2ULL << lane) - 1ULL);
            const int nxt = above ? (__ffsll((unsigned long long)above) - 1) : 64;
            const int len = nxt - lane;                 // 1..64
            if (phase == 0) {
                atomicAdd(&histcur[key], 1);
            } else {
                const int slot = atomicAdd(&histcur[key], 1);
                if (slot < ITEM_CAP)
                    items[slot] = ((unsigned)wave << 14) | ((unsigned)j << 6)
                                | (unsigned)(len - 1);
            }
        }
    }
}

// ---- exclusive scan over NTILES bins ----
__global__ __launch_bounds__(1024) void scan_kernel(
    const int* __restrict__ hist, int* __restrict__ offs, int* __restrict__ cursor)
{
    __shared__ int part[1024];
    const int t = threadIdx.x;
    const int base = t * 8;
    int loc[8]; int s = 0;
    #pragma unroll
    for (int i = 0; i < 8; ++i) {
        const int h = (base + i < NTILES) ? hist[base + i] : 0;
        loc[i] = s; s += h;
    }
    part[t] = s;
    __syncthreads();
    for (int off = 1; off < 1024; off <<= 1) {
        int v = 0;
        if (t >= off) v = part[t - off];
        __syncthreads();
        part[t] += v;
        __syncthreads();
    }
    const int excl = (t > 0) ? part[t - 1] : 0;
    #pragma unroll
    for (int i = 0; i < 8; ++i) {
        if (base + i < NTILES) {
            offs[base + i]   = excl + loc[i];
            cursor[base + i] = excl + loc[i];
        }
    }
    if (t == 1023) offs[NTILES] = part[1023];
}

// ---- pass A: per-tile forward; image tile in LDS; fast weight ----
__global__ __launch_bounds__(256) void tileA_kernel(
    const float* __restrict__ image, const LorT* __restrict__ lortab,
    const int* __restrict__ offs, const unsigned* __restrict__ items,
    float* __restrict__ p)
{
    const int b = blockIdx.x;
    const int i0 = offs[b], i1 = min(offs[b + 1], ITEM_CAP);
    if (i0 >= i1) return;
    const int tx0 = (b / 400) << 3, ty0 = ((b / 20) % 20) << 3, tz0 = (b % 20) << 3;
    __shared__ float img[512];
    const int t = threadIdx.x;
    for (int v = t; v < 512; v += 256) {
        const int lx = v >> 6, ly = (v >> 3) & 7, lz = v & 7;
        img[v] = image[(size_t)(tx0 + lx) * 25600 + (ty0 + ly) * 160 + (tz0 + lz)];
    }
    __syncthreads();
    for (int idx = i0 + t; idx < i1; idx += 256) {
        const unsigned it = items[idx];
        const int lor = (int)(it >> 14);
        const int js  = (int)((it >> 6) & 255);
        const int len = (int)(it & 63) + 1;
        const float4 A = lortab[lor].a, B = lortab[lor].b;
        const float dl = B.w * (1.0f / 256.0f);
        const float s_tof = A.w * 0.15f;
        float pp = 0.0f;
        for (int m = 0; m < len; ++m) {
            int ix, iy, iz; float e;
            if (sample_vox(js + m, A.x, A.y, A.z, B.x, B.y, B.z, B.w, s_tof,
                           ix, iy, iz, e)) {
                const int lx = ix - tx0, ly = iy - ty0, lz = iz - tz0;
                if ((unsigned)lx < 8u && (unsigned)ly < 8u && (unsigned)lz < 8u)
                    pp += img[(lx << 6) | (ly << 3) | lz] * (__expf(-e) * dl);
            }
        }
        atomicAdd(&p[lor], pp);
    }
}

// ---- pass B (fused finalize): LDS bp tile, then out = image/(eff+eps)*bp ----
__global__ __launch_bounds__(256) void tileB_kernel(
    const float* __restrict__ image, const float* __restrict__ effmap,
    const LorT* __restrict__ lortab, const int* __restrict__ offs,
    const unsigned* __restrict__ items, const float* __restrict__ p,
    float* __restrict__ out)
{
    const int b = blockIdx.x;
    const int i0 = offs[b], i1 = min(offs[b + 1], ITEM_CAP);
    if (i0 >= i1) return;                 // uncovered tile: out stays 0 (memset)
    const int tx0 = (b / 400) << 3, ty0 = ((b / 20) % 20) << 3, tz0 = (b % 20) << 3;
    __shared__ float acc[512];
    const int t = threadIdx.x;
    for (int v = t; v < 512; v += 256) acc[v] = 0.0f;
    __syncthreads();
    for (int idx = i0 + t; idx < i1; idx += 256) {
        const unsigned it = items[idx];
        const int lor = (int)(it >> 14);
        const int js  = (int)((it >> 6) & 255);
        const int len = (int)(it & 63) + 1;
        const float4 A = lortab[lor].a, B = lortab[lor].b;
        const float dl = B.w * (1.0f / 256.0f);
        const float s_tof = A.w * 0.15f;
        const float pv = p[lor];
        for (int m = 0; m < len; ++m) {
            int ix, iy, iz; float e;
            if (sample_vox(js + m, A.x, A.y, A.z, B.x, B.y, B.z, B.w, s_tof,
                           ix, iy, iz, e)) {
                const int lx = ix - tx0, ly = iy - ty0, lz = iz - tz0;
                if ((unsigned)lx < 8u && (unsigned)ly < 8u && (unsigned)lz < 8u)
                    atomicAdd(&acc[(lx << 6) | (ly << 3) | lz],
                              pv * (__expf(-e) * dl));
            }
        }
    }
    __syncthreads();
    for (int v = t; v < 512; v += 256) {
        const int lx = v >> 6, ly = (v >> 3) & 7, lz = v & 7;
        const size_t g = (size_t)(tx0 + lx) * 25600 + (ty0 + ly) * 160 + (tz0 + lz);
        out[g] = image[g] / (effmap[g] + 1e-8f) * acc[v];
    }
}

// ---- fallback (R5): direct trace with global atomics ----
__global__ __launch_bounds__(256) void trace_direct_kernel(
    const float* __restrict__ image, const float* __restrict__ lors,
    float* __restrict__ bp, int n_lors)
{
#pragma clang fp contract(off)
    const int wave = (int)((blockIdx.x * blockDim.x + threadIdx.x) >> 6);
    const int lane = threadIdx.x & 63;
    if (wave >= n_lors) return;
    const float* l = lors + (size_t)wave * 7;
    const float p0x = l[0], p0y = l[1], p0z = l[2];
    const float dx = l[3] - p0x, dy = l[4] - p0y, dz = l[5] - p0z;
    const float tof = l[6];
    const float L  = sqrtf(dx * dx + dy * dy + dz * dz);
    const float dl = L * (1.0f / 256.0f);
    const float s_tof = tof * 0.15f;
    int j0, j1;
    lor_window(p0x, p0y, p0z, dx, dy, dz, L, s_tof, j0, j1);
    const int nk = (j1 - j0 + 64) >> 6;
    if (nk <= 0) return;
    int flat[4]; float w[4]; float psum = 0.0f;
    for (int k = 0; k < nk; ++k) {
        const int j = j0 + lane + (k << 6);
        int ix, iy, iz; float e; float wk = 0.0f; int fl = 0;
        if (j <= j1 &&
            sample_vox(j, p0x, p0y, p0z, dx, dy, dz, L, s_tof, ix, iy, iz, e)) {
            wk = __expf(-e) * dl;
            fl = ix * 25600 + iy * 160 + iz;
            psum += image[fl] * wk;
        }
        flat[k] = fl; w[k] = wk;
    }
    #pragma unroll
    for (int off = 32; off >= 1; off >>= 1) psum += __shfl_xor(psum, off, 64);
    for (int k = 0; k < nk; ++k)
        if (w[k] > 0.0f) atomicAdd(&bp[flat[k]], psum * w[k]);
}

__global__ __launch_bounds__(256) void finalize_kernel(
    const float4* __restrict__ image, const float4* __restrict__ effmap,
    float4* __restrict__ out, int n4)
{
    const int i = blockIdx.x * blockDim.x + threadIdx.x;
    if (i >= n4) return;
    const float4 im = image[i];
    const float4 ef = effmap[i];
    float4 b = out[i];
    b.x = im.x / (ef.x + 1e-8f) * b.x;
    b.y = im.y / (ef.y + 1e-8f) * b.y;
    b.z = im.z / (ef.z + 1e-8f) * b.z;
    b.w = im.w / (ef.w + 1e-8f) * b.w;
    out[i] = b;
}

extern "C" void kernel_launch(void* const* d_in, const int* in_sizes, int n_in,
                              void* d_out, int out_size, void* d_ws, size_t ws_size,
                              hipStream_t stream) {
    const float* image  = (const float*)d_in[0];
    const float* effmap = (const float*)d_in[1];
    const float* lors   = (const float*)d_in[2];
    float* out = (float*)d_out;
    const int n = in_sizes[2] / 7;

    char* ws = (char*)d_ws;
    const size_t hist_off   = 0;
    const size_t offs_off   = hist_off + 32768;
    const size_t cursor_off = offs_off + 32768;
    const size_t p_off      = cursor_off + 32768;
    const size_t lortab_off = p_off + (((size_t)n * 4 + 255) & ~(size_t)255);
    const size_t items_off  = lortab_off + (size_t)n * sizeof(LorT);
    const size_t total      = items_off + (size_t)ITEM_CAP * 4;

    hipMemsetAsync(out, 0, (size_t)NVOX * sizeof(float), stream);

    if (ws_size >= total && n < (1 << 17)) {
        int*      hist   = (int*)(ws + hist_off);
        int*      offs   = (int*)(ws + offs_off);
        int*      cursor = (int*)(ws + cursor_off);
        float*    p      = (float*)(ws + p_off);
        LorT*     lortab = (LorT*)(ws + lortab_off);
        unsigned* items  = (unsigned*)(ws + items_off);

        hipMemsetAsync(hist, 0, NTILES * sizeof(int), stream);
        hipMemsetAsync(p, 0, (size_t)n * sizeof(float), stream);

        const int blocksE = (n + 3) / 4;   // 4 waves/block, wave per LOR
        emit_kernel<<<blocksE, 256, 0, stream>>>(lors, lortab, hist, items, n, 0);
        scan_kernel<<<1, 1024, 0, stream>>>(hist, offs, cursor);
        emit_kernel<<<blocksE, 256, 0, stream>>>(lors, lortab, cursor, items, n, 1);
        tileA_kernel<<<NTILES, 256, 0, stream>>>(image, lortab, offs, items, p);
        tileB_kernel<<<NTILES, 256, 0, stream>>>(image, effmap, lortab, offs, items,
                                                 p, out);
    } else {
        trace_direct_kernel<<<(n + 3) / 4, 256, 0, stream>>>(image, lors, out, n);
        const int n4 = NVOX / 4;
        finalize_kernel<<<(n4 + 255) / 256, 256, 0, stream>>>(
            (const float4*)image, (const float4*)effmap, (float4*)out, n4);
    }
}